// Round 7
// baseline (219.053 us; speedup 1.0000x reference)
//
#include <hip/hip_runtime.h>

typedef _Float16 f16;
typedef _Float16 f16x8 __attribute__((ext_vector_type(8)));
typedef _Float16 f16x4 __attribute__((ext_vector_type(4)));
typedef float    f32x4 __attribute__((ext_vector_type(4)));

#define DEV __device__ __forceinline__

static constexpr int Tn = 2048;      // sequence length
static constexpr int Dn = 1024;      // model dim
static constexpr int Mn = 2 * Tn;    // 4096 rows (B*T)
static constexpr int NQKV = 3 * Dn;  // 3072

DEV void gld16(const void* g, void* l) {
  __builtin_amdgcn_global_load_lds((const __attribute__((address_space(1))) unsigned int*)g,
                                   (__attribute__((address_space(3))) unsigned int*)l, 16, 0, 0);
}

// pack 4 f32 -> f16x4 (2x v_cvt_pkrtz_f16_f32)
DEV f16x4 pk4(float a, float b, float c, float d) {
  unsigned int lo = __builtin_bit_cast(unsigned int, __builtin_amdgcn_cvt_pkrtz(a, b));
  unsigned int hi = __builtin_bit_cast(unsigned int, __builtin_amdgcn_cvt_pkrtz(c, d));
  unsigned long long u = (unsigned long long)lo | ((unsigned long long)hi << 32);
  return __builtin_bit_cast(f16x4, u);
}

// ---------------- prep: cast x (f32->f16) + transpose/cast/permute weights ----------------
__global__ __launch_bounds__(256) void k_prep(const float* __restrict__ x, const float* __restrict__ wq,
                                              const float* __restrict__ wk, const float* __restrict__ wv,
                                              const float* __restrict__ wo, f16* __restrict__ xb,
                                              f16* __restrict__ wcat_t, f16* __restrict__ wot) {
  int bid = blockIdx.x;
  if (bid < 4096) {
    int i = bid * 256 + threadIdx.x;           // < Mn*Dn/4
    float4 v = ((const float4*)x)[i];
    f16x4 o4; o4.x = (f16)v.x; o4.y = (f16)v.y; o4.z = (f16)v.z; o4.w = (f16)v.w;
    ((f16x4*)xb)[i] = o4;
    return;
  }
  __shared__ float tile[64][65];
  int wb = bid - 4096;                          // 0..1023
  int z = wb >> 8;                              // 0..3 : wq,wk,wv,wo
  int rb = wb & 255;
  int k0 = (rb >> 4) * 64, n0 = (rb & 15) * 64;
  const float* srcs[4] = {wq, wk, wv, wo};
  const float* w = srcs[z];
  f16* dst = (z == 3) ? wot : wcat_t + (size_t)z * Dn * Dn;
#pragma unroll
  for (int p = 0; p < 16; ++p) {
    int flat = threadIdx.x + p * 256;
    int kl = flat >> 6, nl = flat & 63;
    tile[kl][nl] = w[(size_t)(k0 + kl) * Dn + n0 + nl];
  }
  __syncthreads();
#pragma unroll
  for (int p = 0; p < 16; ++p) {
    int flat = threadIdx.x + p * 256;
    int nl = flat >> 6, kl = flat & 63;
    int c = n0 + nl;
    int cp = (z == 3) ? c : (((c & 15) << 6) | (c >> 4));   // head-contiguous permute for q/k/v
    dst[(size_t)cp * Dn + k0 + kl] = (f16)tile[kl][nl];
  }
}

// ---------------- QKV GEMM (128x128 tile) with fused per-head RMSNorm epilogue ----------------
__global__ __launch_bounds__(256) void k_gemm_qkv(const f16* __restrict__ A, const f16* __restrict__ Bt,
                                                  const float* __restrict__ qw, const float* __restrict__ kw,
                                                  f16* __restrict__ qatt, f16* __restrict__ katt,
                                                  f16* __restrict__ vatt) {
  constexpr int K = 1024;
  __shared__ __align__(16) f16 As[128 * 64];
  __shared__ __align__(16) f16 Bs[128 * 64];
  const int lane = threadIdx.x & 63, wid = threadIdx.x >> 6;
  const int m0 = blockIdx.y * 128;
  const int n0 = blockIdx.x * 128;
  const int wr = (wid >> 1) * 64, wc = (wid & 1) * 64;
  f32x4 acc[4][4];
#pragma unroll
  for (int i = 0; i < 4; ++i)
#pragma unroll
    for (int j = 0; j < 4; ++j) acc[i][j] = (f32x4){0.f, 0.f, 0.f, 0.f};

  char* AsB = (char*)As; char* BsB = (char*)Bs;
  for (int k0 = 0; k0 < K; k0 += 64) {
    __syncthreads();
#pragma unroll
    for (int it = 0; it < 4; ++it) {
      int flat = ((wid * 4 + it) * 64 + lane) * 16;
      int row = flat >> 7, g = (flat >> 4) & 7;
      int sw = (g ^ (row & 7)) << 4;
      gld16((const char*)A + ((size_t)(m0 + row) * K + k0) * 2 + sw, AsB + (wid * 4 + it) * 1024);
      gld16((const char*)Bt + ((size_t)(n0 + row) * K + k0) * 2 + sw, BsB + (wid * 4 + it) * 1024);
    }
    __syncthreads();
#pragma unroll
    for (int kk = 0; kk < 2; ++kk) {
      f16x8 af[4], bf[4];
#pragma unroll
      for (int ms = 0; ms < 4; ++ms) {
        int r = wr + ms * 16 + (lane & 15);
        af[ms] = *(const f16x8*)(AsB + r * 128 + (((kk * 4 + (lane >> 4)) ^ (r & 7)) << 4));
      }
#pragma unroll
      for (int ns = 0; ns < 4; ++ns) {
        int r = wc + ns * 16 + (lane & 15);
        bf[ns] = *(const f16x8*)(BsB + r * 128 + (((kk * 4 + (lane >> 4)) ^ (r & 7)) << 4));
      }
#pragma unroll
      for (int ms = 0; ms < 4; ++ms)
#pragma unroll
        for (int ns = 0; ns < 4; ++ns)
          acc[ms][ns] = __builtin_amdgcn_mfma_f32_16x16x32_f16(af[ms], bf[ns], acc[ms][ns], 0, 0, 0);
    }
  }

  // fused epilogue: per (row, head) RMSNorm for q/k, pass-through for v
  const int rq = lane >> 4, cq = lane & 15;
  const int sec = blockIdx.x >> 3;                         // 0=q 1=k 2=v
  const int hwave = (((blockIdx.x & 7) * 128) + wc) >> 6;  // head 0..15
  f16* dst = (sec == 0) ? qatt : (sec == 1) ? katt : vatt;
  float wv[4];
#pragma unroll
  for (int ns = 0; ns < 4; ++ns) {
    if (sec == 0)      wv[ns] = qw[ns * 16 + cq] * 0.18033688011116013f;  // 0.125*log2(e)
    else if (sec == 1) wv[ns] = kw[ns * 16 + cq];
    else               wv[ns] = 1.f;
  }
#pragma unroll
  for (int ms = 0; ms < 4; ++ms) {
#pragma unroll
    for (int r = 0; r < 4; ++r) {
      int row = m0 + wr + ms * 16 + rq * 4 + r;
      float sc = 1.f;
      if (sec < 2) {
        float ss = 0.f;
#pragma unroll
        for (int ns = 0; ns < 4; ++ns) ss += acc[ms][ns][r] * acc[ms][ns][r];
        ss += __shfl_xor(ss, 1, 64);
        ss += __shfl_xor(ss, 2, 64);
        ss += __shfl_xor(ss, 4, 64);
        ss += __shfl_xor(ss, 8, 64);
        sc = rsqrtf(ss * (1.f / 64) + 1e-5f);
      }
      int b = row >> 11, t = row & 2047;
      size_t base = ((size_t)(b * 16 + hwave) * Tn + t) * 64;
#pragma unroll
      for (int ns = 0; ns < 4; ++ns)
        dst[base + ns * 16 + cq] = (f16)(acc[ms][ns][r] * sc * wv[ns]);
    }
  }
}

// ---------------- V transpose: vt[bh][d][t] = vatt[bh][t][d] ----------------
__global__ __launch_bounds__(256) void k_vtrans(const f16* __restrict__ vatt, f16* __restrict__ vt) {
  __shared__ f16 tile[64][72];
  int t0 = blockIdx.x * 64, bh = blockIdx.y;
  const f16* src = vatt + ((size_t)bh * Tn + t0) * 64;
#pragma unroll
  for (int p = 0; p < 2; ++p) {
    int c = threadIdx.x + p * 256;     // 0..511
    int tl = c >> 3, dc = (c & 7) * 8;
    f16x8 v = *(const f16x8*)(src + (size_t)tl * 64 + dc);
#pragma unroll
    for (int j = 0; j < 8; ++j) tile[dc + j][tl] = v[j];
  }
  __syncthreads();
#pragma unroll
  for (int p = 0; p < 2; ++p) {
    int c = threadIdx.x + p * 256;
    int d = c >> 3, tc = (c & 7) * 8;
    f16x8 o;
#pragma unroll
    for (int j = 0; j < 8; ++j) o[j] = tile[d][tc + j];
    *(f16x8*)(vt + ((size_t)bh * 64 + d) * Tn + t0 + tc) = o;
  }
}

// ---------------- flash attention: 4 waves x 32 q-rows (2 groups of 16), KVBLK=64 ----------------
// Chained-MFMA softmax path: swapped QK^T (mfma_16x16x32(K,Q)) leaves S^T with
// col=q,row=kv per lane — exactly the B-fragment layout of mfma_f32_16x16x16f16.
// P^T = cvt_pkrtz(exp2(S)) feeds PV^T = mfma(A=V^T_sub, B=P^T_sub) DIRECTLY from
// registers: no P LDS round-trip, no bank conflicts. Output O^T (col=q per lane)
// makes 1/psum a per-lane multiply; one LDS transpose per block at epilogue.
// QBLK=32/wave amortizes the K/V LDS tile reads over 2x the q-rows (LDS-bound fix).
__global__ __launch_bounds__(256) void k_attn(const f16* __restrict__ qatt, const f16* __restrict__ katt,
                                              const f16* __restrict__ vt, f16* __restrict__ attout) {
  __shared__ __align__(16) f16 Ks[2][64 * 64];   // 16KB, reused as transpose buf at epilogue
  __shared__ __align__(16) f16 Vs[2][64 * 64];   // 16KB
  const int lane = threadIdx.x & 63, wid = threadIdx.x >> 6;
  const int q = lane & 15, g = lane >> 4;
  const int bh = blockIdx.y, b = bh >> 4, h = bh & 15;
  const int tq0 = blockIdx.x * 128 + wid * 32;

  const f16* qbase = qatt + ((size_t)bh * Tn + tq0) * 64;
  f16x8 qf[2][2];
#pragma unroll
  for (int qg = 0; qg < 2; ++qg)
#pragma unroll
    for (int kk = 0; kk < 2; ++kk)
      qf[qg][kk] = *(const f16x8*)(qbase + (size_t)(qg * 16 + q) * 64 + kk * 32 + g * 8);

  f32x4 o[4][2];                 // O^T[dt*16+g*4+r][q] per qg
#pragma unroll
  for (int i = 0; i < 4; ++i)
#pragma unroll
    for (int j = 0; j < 2; ++j) o[i][j] = (f32x4){0.f, 0.f, 0.f, 0.f};
  float psum[2] = {0.f, 0.f};

  const char* kgb = (const char*)(katt + (size_t)bh * Tn * 64);
  const char* vgb = (const char*)(vt + (size_t)bh * 64 * Tn);
  char* KsB = (char*)Ks; char* VsB = (char*)Vs;

  auto stage = [&](int buf, int kt) {
    int k0 = kt * 64;
#pragma unroll
    for (int it = 0; it < 2; ++it) {
      int flat = ((wid * 2 + it) * 64 + lane) * 16;
      int row = flat >> 7, gg = (flat >> 4) & 7;
      int sw = (gg ^ (row & 7)) << 4;
      gld16(kgb + ((size_t)(k0 + row) * 64) * 2 + sw, KsB + buf * 8192 + (wid * 2 + it) * 1024);
      gld16(vgb + ((size_t)row * Tn + k0) * 2 + sw, VsB + buf * 8192 + (wid * 2 + it) * 1024);
    }
  };

  constexpr int NT = Tn / 64;
  stage(0, 0);

  for (int kt = 0; kt < NT; ++kt) {
    const int cur = kt & 1;
    const char* Kc = KsB + cur * 8192;
    const char* Vc = VsB + cur * 8192;
    if (kt + 1 < NT) {
      stage(cur ^ 1, kt + 1);
      asm volatile("s_waitcnt vmcnt(4)" ::: "memory");
    } else {
      asm volatile("s_waitcnt vmcnt(0)" ::: "memory");
    }
    __builtin_amdgcn_s_barrier();
    __builtin_amdgcn_sched_barrier(0);

    // S^T = K Q : s[sub][qg][r] = S[kv=sub*16+g*4+r][q] (q within group qg)
    f32x4 s[4][2];
    __builtin_amdgcn_s_setprio(1);
#pragma unroll
    for (int sub = 0; sub < 4; ++sub) {
      int kr = sub * 16 + q;
      f16x8 kf0 = *(const f16x8*)(Kc + kr * 128 + (((0 + g) ^ (kr & 7)) << 4));
      f16x8 kf1 = *(const f16x8*)(Kc + kr * 128 + (((4 + g) ^ (kr & 7)) << 4));
#pragma unroll
      for (int qg = 0; qg < 2; ++qg) {
        f32x4 z = (f32x4){0.f, 0.f, 0.f, 0.f};
        z = __builtin_amdgcn_mfma_f32_16x16x32_f16(kf0, qf[qg][0], z, 0, 0, 0);
        s[sub][qg] = __builtin_amdgcn_mfma_f32_16x16x32_f16(kf1, qf[qg][1], z, 0, 0, 0);
      }
    }
    __builtin_amdgcn_s_setprio(0);

    // P^T = exp2(S^T) packed to f16x4 B-fragments (pure registers, no LDS)
    f16x4 pb[4][2];
#pragma unroll
    for (int sub = 0; sub < 4; ++sub)
#pragma unroll
      for (int qg = 0; qg < 2; ++qg) {
        float e0 = __builtin_amdgcn_exp2f(s[sub][qg][0]);
        float e1 = __builtin_amdgcn_exp2f(s[sub][qg][1]);
        float e2 = __builtin_amdgcn_exp2f(s[sub][qg][2]);
        float e3 = __builtin_amdgcn_exp2f(s[sub][qg][3]);
        psum[qg] += (e0 + e1) + (e2 + e3);
        pb[sub][qg] = pk4(e0, e1, e2, e3);
      }

    // O^T += V^T P^T  (A = V^T[16d][16kv] sub-tiles via b64 reads, B = pb)
    __builtin_amdgcn_s_setprio(1);
#pragma unroll
    for (int dt = 0; dt < 4; ++dt) {
      int dr = dt * 16 + q;           // d row; dr&7 == q&7
#pragma unroll
      for (int ks = 0; ks < 4; ++ks) {
        f16x4 va = *(const f16x4*)(Vc + dr * 128 + (((ks * 2 + (g >> 1)) ^ (q & 7)) << 4) + (g & 1) * 8);
#pragma unroll
        for (int qg = 0; qg < 2; ++qg)
          o[dt][qg] = __builtin_amdgcn_mfma_f32_16x16x16f16(va, pb[ks][qg], o[dt][qg], 0, 0, 0);
      }
    }
    __builtin_amdgcn_s_setprio(0);
    __builtin_amdgcn_s_barrier();   // all waves done reading buf[cur] before restage
  }

  // epilogue: psum reduce (lanes q,q+16,q+32,q+48), per-lane normalize (col=q!),
  // LDS transpose (reuse Ks, [128 q][64 d] f16, chunk XOR by qrow&7), coalesced store.
#pragma unroll
  for (int qg = 0; qg < 2; ++qg) {
    psum[qg] += __shfl_xor(psum[qg], 16, 64);
    psum[qg] += __shfl_xor(psum[qg], 32, 64);
  }
  float inv[2] = {1.f / psum[0], 1.f / psum[1]};
  char* TsB = (char*)Ks;
#pragma unroll
  for (int dt = 0; dt < 4; ++dt)
#pragma unroll
    for (int qg = 0; qg < 2; ++qg) {
      f16x4 pv = pk4(o[dt][qg][0] * inv[qg], o[dt][qg][1] * inv[qg],
                     o[dt][qg][2] * inv[qg], o[dt][qg][3] * inv[qg]);
      int qrow = wid * 32 + qg * 16 + q;
      int c = dt * 2 + (g >> 1);
      char* p = TsB + qrow * 128 + ((c ^ (qrow & 7)) << 4) + (g & 1) * 8;
      *(unsigned long long*)p = __builtin_bit_cast(unsigned long long, pv);
    }
  __syncthreads();
  {
    int qrow = threadIdx.x >> 1, half = threadIdx.x & 1;
    f16* gdst = attout + ((size_t)(b * Tn) + blockIdx.x * 128 + qrow) * Dn + h * 64 + half * 32;
#pragma unroll
    for (int j = 0; j < 4; ++j) {
      int hc = half * 4 + j;
      f16x8 vv = *(const f16x8*)(TsB + qrow * 128 + ((hc ^ (qrow & 7)) << 4));
      *(f16x8*)(gdst + j * 8) = vv;
    }
  }
}

// ---------------- out-proj GEMM: 64x128 tile (2 blocks/CU for occupancy) ----------------
__global__ __launch_bounds__(256) void k_gemm_o(const f16* __restrict__ A, const f16* __restrict__ Bt,
                                                float* __restrict__ C, int N, int K) {
  __shared__ __align__(16) f16 As[64 * 64];
  __shared__ __align__(16) f16 Bs[128 * 64];
  const int lane = threadIdx.x & 63, wid = threadIdx.x >> 6;
  const int m0 = blockIdx.y * 64, n0 = blockIdx.x * 128;
  const int wr = (wid >> 1) * 32, wc = (wid & 1) * 64;
  f32x4 acc[2][4];
#pragma unroll
  for (int i = 0; i < 2; ++i)
#pragma unroll
    for (int j = 0; j < 4; ++j) acc[i][j] = (f32x4){0.f, 0.f, 0.f, 0.f};

  char* AsB = (char*)As; char* BsB = (char*)Bs;
  for (int k0 = 0; k0 < K; k0 += 64) {
    __syncthreads();
#pragma unroll
    for (int it = 0; it < 2; ++it) {
      int flat = ((wid * 2 + it) * 64 + lane) * 16;
      int row = flat >> 7, g = (flat >> 4) & 7;
      int sw = (g ^ (row & 7)) << 4;
      gld16((const char*)A + ((size_t)(m0 + row) * K + k0) * 2 + sw, AsB + (wid * 2 + it) * 1024);
    }
#pragma unroll
    for (int it = 0; it < 4; ++it) {
      int flat = ((wid * 4 + it) * 64 + lane) * 16;
      int row = flat >> 7, g = (flat >> 4) & 7;
      int sw = (g ^ (row & 7)) << 4;
      gld16((const char*)Bt + ((size_t)(n0 + row) * K + k0) * 2 + sw, BsB + (wid * 4 + it) * 1024);
    }
    __syncthreads();
#pragma unroll
    for (int kk = 0; kk < 2; ++kk) {
      f16x8 af[2], bf[4];
#pragma unroll
      for (int ms = 0; ms < 2; ++ms) {
        int r = wr + ms * 16 + (lane & 15);
        af[ms] = *(const f16x8*)(AsB + r * 128 + (((kk * 4 + (lane >> 4)) ^ (r & 7)) << 4));
      }
#pragma unroll
      for (int ns = 0; ns < 4; ++ns) {
        int r = wc + ns * 16 + (lane & 15);
        bf[ns] = *(const f16x8*)(BsB + r * 128 + (((kk * 4 + (lane >> 4)) ^ (r & 7)) << 4));
      }
#pragma unroll
      for (int ms = 0; ms < 2; ++ms)
#pragma unroll
        for (int ns = 0; ns < 4; ++ns)
          acc[ms][ns] = __builtin_amdgcn_mfma_f32_16x16x32_f16(af[ms], bf[ns], acc[ms][ns], 0, 0, 0);
    }
  }
  const int rq = lane >> 4, cq = lane & 15;
#pragma unroll
  for (int ms = 0; ms < 2; ++ms)
#pragma unroll
    for (int ns = 0; ns < 4; ++ns)
#pragma unroll
      for (int r = 0; r < 4; ++r)
        C[(size_t)(m0 + wr + ms * 16 + rq * 4 + r) * N + n0 + wc + ns * 16 + cq] = acc[ms][ns][r];
}

// ---------------- host launch ----------------
extern "C" void kernel_launch(void* const* d_in, const int* in_sizes, int n_in,
                              void* d_out, int out_size, void* d_ws, size_t ws_size,
                              hipStream_t stream) {
  const float* x  = (const float*)d_in[0];
  const float* wq = (const float*)d_in[1];
  const float* wk = (const float*)d_in[2];
  const float* wv = (const float*)d_in[3];
  const float* wo = (const float*)d_in[4];
  const float* qw = (const float*)d_in[5];
  const float* kw = (const float*)d_in[6];

  char* ws = (char*)d_ws;
  const size_t MB = 1 << 20;
  f16* xb     = (f16*)(ws + 0 * MB);    // 8 MB
  f16* wcat   = (f16*)(ws + 8 * MB);    // 6 MB  [3072][1024] head-contiguous rows
  f16* wot    = (f16*)(ws + 14 * MB);   // 2 MB  [1024][1024] = Wo^T
  f16* qatt   = (f16*)(ws + 16 * MB);   // 8 MB  [32][2048][64]
  f16* katt   = (f16*)(ws + 24 * MB);   // 8 MB
  f16* vatt   = (f16*)(ws + 32 * MB);   // 8 MB
  f16* vtb    = (f16*)(ws + 40 * MB);   // 8 MB  [32][64][2048]
  f16* attout = (f16*)(ws + 48 * MB);   // 8 MB  [4096][1024]

  k_prep<<<dim3(5120), 256, 0, stream>>>(x, wq, wk, wv, wo, xb, wcat, wot);
  k_gemm_qkv<<<dim3(NQKV / 128, Mn / 128), 256, 0, stream>>>(xb, wcat, qw, kw, qatt, katt, vatt);
  k_vtrans<<<dim3(Tn / 64, 32), 256, 0, stream>>>(vatt, vtb);
  k_attn<<<dim3(Tn / 128, 32), 256, 0, stream>>>(qatt, katt, vtb, attout);
  k_gemm_o<<<dim3(Dn / 128, Mn / 64), 256, 0, stream>>>(attout, wot, (float*)d_out, Dn, Dn);
}

// Round 8
// 218.766 us; speedup vs baseline: 1.0013x; 1.0013x over previous
//
#include <hip/hip_runtime.h>

typedef _Float16 f16;
typedef _Float16 f16x8 __attribute__((ext_vector_type(8)));
typedef _Float16 f16x4 __attribute__((ext_vector_type(4)));
typedef float    f32x4 __attribute__((ext_vector_type(4)));

#define DEV __device__ __forceinline__

static constexpr int Tn = 2048;      // sequence length
static constexpr int Dn = 1024;      // model dim
static constexpr int Mn = 2 * Tn;    // 4096 rows (B*T)
static constexpr int NQKV = 3 * Dn;  // 3072

DEV void gld16(const void* g, void* l) {
  __builtin_amdgcn_global_load_lds((const __attribute__((address_space(1))) unsigned int*)g,
                                   (__attribute__((address_space(3))) unsigned int*)l, 16, 0, 0);
}

// pack 4 f32 -> f16x4 (2x v_cvt_pkrtz_f16_f32)
DEV f16x4 pk4(float a, float b, float c, float d) {
  unsigned int lo = __builtin_bit_cast(unsigned int, __builtin_amdgcn_cvt_pkrtz(a, b));
  unsigned int hi = __builtin_bit_cast(unsigned int, __builtin_amdgcn_cvt_pkrtz(c, d));
  unsigned long long u = (unsigned long long)lo | ((unsigned long long)hi << 32);
  return __builtin_bit_cast(f16x4, u);
}

// ---------------- prep: cast x (f32->f16) + transpose/cast/permute weights ----------------
__global__ __launch_bounds__(256) void k_prep(const float* __restrict__ x, const float* __restrict__ wq,
                                              const float* __restrict__ wk, const float* __restrict__ wv,
                                              const float* __restrict__ wo, f16* __restrict__ xb,
                                              f16* __restrict__ wcat_t, f16* __restrict__ wot) {
  int bid = blockIdx.x;
  if (bid < 4096) {
    int i = bid * 256 + threadIdx.x;           // < Mn*Dn/4
    float4 v = ((const float4*)x)[i];
    f16x4 o4; o4.x = (f16)v.x; o4.y = (f16)v.y; o4.z = (f16)v.z; o4.w = (f16)v.w;
    ((f16x4*)xb)[i] = o4;
    return;
  }
  __shared__ float tile[64][65];
  int wb = bid - 4096;                          // 0..1023
  int z = wb >> 8;                              // 0..3 : wq,wk,wv,wo
  int rb = wb & 255;
  int k0 = (rb >> 4) * 64, n0 = (rb & 15) * 64;
  const float* srcs[4] = {wq, wk, wv, wo};
  const float* w = srcs[z];
  f16* dst = (z == 3) ? wot : wcat_t + (size_t)z * Dn * Dn;
#pragma unroll
  for (int p = 0; p < 16; ++p) {
    int flat = threadIdx.x + p * 256;
    int kl = flat >> 6, nl = flat & 63;
    tile[kl][nl] = w[(size_t)(k0 + kl) * Dn + n0 + nl];
  }
  __syncthreads();
#pragma unroll
  for (int p = 0; p < 16; ++p) {
    int flat = threadIdx.x + p * 256;
    int nl = flat >> 6, kl = flat & 63;
    int c = n0 + nl;
    int cp = (z == 3) ? c : (((c & 15) << 6) | (c >> 4));   // head-contiguous permute for q/k/v
    dst[(size_t)cp * Dn + k0 + kl] = (f16)tile[kl][nl];
  }
}

// ---------------- QKV GEMM (128x128 tile) with fused per-head RMSNorm epilogue ----------------
__global__ __launch_bounds__(256) void k_gemm_qkv(const f16* __restrict__ A, const f16* __restrict__ Bt,
                                                  const float* __restrict__ qw, const float* __restrict__ kw,
                                                  f16* __restrict__ qatt, f16* __restrict__ katt,
                                                  f16* __restrict__ vatt) {
  constexpr int K = 1024;
  __shared__ __align__(16) f16 As[128 * 64];
  __shared__ __align__(16) f16 Bs[128 * 64];
  const int lane = threadIdx.x & 63, wid = threadIdx.x >> 6;
  const int m0 = blockIdx.y * 128;
  const int n0 = blockIdx.x * 128;
  const int wr = (wid >> 1) * 64, wc = (wid & 1) * 64;
  f32x4 acc[4][4];
#pragma unroll
  for (int i = 0; i < 4; ++i)
#pragma unroll
    for (int j = 0; j < 4; ++j) acc[i][j] = (f32x4){0.f, 0.f, 0.f, 0.f};

  char* AsB = (char*)As; char* BsB = (char*)Bs;
  for (int k0 = 0; k0 < K; k0 += 64) {
    __syncthreads();
#pragma unroll
    for (int it = 0; it < 4; ++it) {
      int flat = ((wid * 4 + it) * 64 + lane) * 16;
      int row = flat >> 7, g = (flat >> 4) & 7;
      int sw = (g ^ (row & 7)) << 4;
      gld16((const char*)A + ((size_t)(m0 + row) * K + k0) * 2 + sw, AsB + (wid * 4 + it) * 1024);
      gld16((const char*)Bt + ((size_t)(n0 + row) * K + k0) * 2 + sw, BsB + (wid * 4 + it) * 1024);
    }
    __syncthreads();
#pragma unroll
    for (int kk = 0; kk < 2; ++kk) {
      f16x8 af[4], bf[4];
#pragma unroll
      for (int ms = 0; ms < 4; ++ms) {
        int r = wr + ms * 16 + (lane & 15);
        af[ms] = *(const f16x8*)(AsB + r * 128 + (((kk * 4 + (lane >> 4)) ^ (r & 7)) << 4));
      }
#pragma unroll
      for (int ns = 0; ns < 4; ++ns) {
        int r = wc + ns * 16 + (lane & 15);
        bf[ns] = *(const f16x8*)(BsB + r * 128 + (((kk * 4 + (lane >> 4)) ^ (r & 7)) << 4));
      }
#pragma unroll
      for (int ms = 0; ms < 4; ++ms)
#pragma unroll
        for (int ns = 0; ns < 4; ++ns)
          acc[ms][ns] = __builtin_amdgcn_mfma_f32_16x16x32_f16(af[ms], bf[ns], acc[ms][ns], 0, 0, 0);
    }
  }

  // fused epilogue: per (row, head) RMSNorm for q/k, pass-through for v
  const int rq = lane >> 4, cq = lane & 15;
  const int sec = blockIdx.x >> 3;                         // 0=q 1=k 2=v
  const int hwave = (((blockIdx.x & 7) * 128) + wc) >> 6;  // head 0..15
  f16* dst = (sec == 0) ? qatt : (sec == 1) ? katt : vatt;
  float wv[4];
#pragma unroll
  for (int ns = 0; ns < 4; ++ns) {
    if (sec == 0)      wv[ns] = qw[ns * 16 + cq] * 0.18033688011116013f;  // 0.125*log2(e)
    else if (sec == 1) wv[ns] = kw[ns * 16 + cq];
    else               wv[ns] = 1.f;
  }
#pragma unroll
  for (int ms = 0; ms < 4; ++ms) {
#pragma unroll
    for (int r = 0; r < 4; ++r) {
      int row = m0 + wr + ms * 16 + rq * 4 + r;
      float sc = 1.f;
      if (sec < 2) {
        float ss = 0.f;
#pragma unroll
        for (int ns = 0; ns < 4; ++ns) ss += acc[ms][ns][r] * acc[ms][ns][r];
        ss += __shfl_xor(ss, 1, 64);
        ss += __shfl_xor(ss, 2, 64);
        ss += __shfl_xor(ss, 4, 64);
        ss += __shfl_xor(ss, 8, 64);
        sc = rsqrtf(ss * (1.f / 64) + 1e-5f);
      }
      int b = row >> 11, t = row & 2047;
      size_t base = ((size_t)(b * 16 + hwave) * Tn + t) * 64;
#pragma unroll
      for (int ns = 0; ns < 4; ++ns)
        dst[base + ns * 16 + cq] = (f16)(acc[ms][ns][r] * sc * wv[ns]);
    }
  }
}

// ---------------- V transpose: vt[bh][d][t] = vatt[bh][t][d] ----------------
__global__ __launch_bounds__(256) void k_vtrans(const f16* __restrict__ vatt, f16* __restrict__ vt) {
  __shared__ f16 tile[64][72];
  int t0 = blockIdx.x * 64, bh = blockIdx.y;
  const f16* src = vatt + ((size_t)bh * Tn + t0) * 64;
#pragma unroll
  for (int p = 0; p < 2; ++p) {
    int c = threadIdx.x + p * 256;     // 0..511
    int tl = c >> 3, dc = (c & 7) * 8;
    f16x8 v = *(const f16x8*)(src + (size_t)tl * 64 + dc);
#pragma unroll
    for (int j = 0; j < 8; ++j) tile[dc + j][tl] = v[j];
  }
  __syncthreads();
#pragma unroll
  for (int p = 0; p < 2; ++p) {
    int c = threadIdx.x + p * 256;
    int d = c >> 3, tc = (c & 7) * 8;
    f16x8 o;
#pragma unroll
    for (int j = 0; j < 8; ++j) o[j] = tile[d][tc + j];
    *(f16x8*)(vt + ((size_t)bh * 64 + d) * Tn + t0 + tc) = o;
  }
}

// ---------------- flash attention: 2 waves x 32 q-rows, KVBLK=64, 1024 blocks ----------------
// Chained-MFMA softmax path (register P^T into mfma_16x16x16 PV), no-max exp2 softmax.
// 2-wave blocks restore latency hiding: 32KB LDS -> 5 blocks/CU = 10 waves/CU, barriers
// sync only 2 waves, ~5 independent tile streams per CU (R6 regression fix).
__global__ __launch_bounds__(128) void k_attn(const f16* __restrict__ qatt, const f16* __restrict__ katt,
                                              const f16* __restrict__ vt, f16* __restrict__ attout) {
  __shared__ __align__(16) f16 Ks[2][64 * 64];   // 16KB, reused as transpose buf at epilogue
  __shared__ __align__(16) f16 Vs[2][64 * 64];   // 16KB
  const int lane = threadIdx.x & 63, wid = threadIdx.x >> 6;   // wid 0..1
  const int q = lane & 15, g = lane >> 4;
  const int bh = blockIdx.y, b = bh >> 4, h = bh & 15;
  const int tq0 = blockIdx.x * 64 + wid * 32;

  const f16* qbase = qatt + ((size_t)bh * Tn + tq0) * 64;
  f16x8 qf[2][2];
#pragma unroll
  for (int qg = 0; qg < 2; ++qg)
#pragma unroll
    for (int kk = 0; kk < 2; ++kk)
      qf[qg][kk] = *(const f16x8*)(qbase + (size_t)(qg * 16 + q) * 64 + kk * 32 + g * 8);

  f32x4 o[4][2];                 // O^T[dt*16+g*4+r][q] per qg
#pragma unroll
  for (int i = 0; i < 4; ++i)
#pragma unroll
    for (int j = 0; j < 2; ++j) o[i][j] = (f32x4){0.f, 0.f, 0.f, 0.f};
  float psum[2] = {0.f, 0.f};

  const char* kgb = (const char*)(katt + (size_t)bh * Tn * 64);
  const char* vgb = (const char*)(vt + (size_t)bh * 64 * Tn);
  char* KsB = (char*)Ks; char* VsB = (char*)Vs;

  // 8 gld16 per wave per tile (4 K + 4 V); 2 waves cover the 16KB tile
  auto stage = [&](int buf, int kt) {
    int k0 = kt * 64;
#pragma unroll
    for (int it = 0; it < 4; ++it) {
      int flat = ((wid * 4 + it) * 64 + lane) * 16;
      int row = flat >> 7, gg = (flat >> 4) & 7;
      int sw = (gg ^ (row & 7)) << 4;
      gld16(kgb + ((size_t)(k0 + row) * 64) * 2 + sw, KsB + buf * 8192 + (wid * 4 + it) * 1024);
      gld16(vgb + ((size_t)row * Tn + k0) * 2 + sw, VsB + buf * 8192 + (wid * 4 + it) * 1024);
    }
  };

  constexpr int NT = Tn / 64;
  stage(0, 0);

  for (int kt = 0; kt < NT; ++kt) {
    const int cur = kt & 1;
    const char* Kc = KsB + cur * 8192;
    const char* Vc = VsB + cur * 8192;
    if (kt + 1 < NT) {
      stage(cur ^ 1, kt + 1);
      asm volatile("s_waitcnt vmcnt(8)" ::: "memory");   // this wave's 8 current-tile loads done
    } else {
      asm volatile("s_waitcnt vmcnt(0)" ::: "memory");
    }
    __builtin_amdgcn_s_barrier();
    __builtin_amdgcn_sched_barrier(0);

    // S^T = K Q : s[sub][qg][r] = S[kv=sub*16+g*4+r][q] (q within group qg)
    f32x4 s[4][2];
    __builtin_amdgcn_s_setprio(1);
#pragma unroll
    for (int sub = 0; sub < 4; ++sub) {
      int kr = sub * 16 + q;
      f16x8 kf0 = *(const f16x8*)(Kc + kr * 128 + (((0 + g) ^ (kr & 7)) << 4));
      f16x8 kf1 = *(const f16x8*)(Kc + kr * 128 + (((4 + g) ^ (kr & 7)) << 4));
#pragma unroll
      for (int qg = 0; qg < 2; ++qg) {
        f32x4 z = (f32x4){0.f, 0.f, 0.f, 0.f};
        z = __builtin_amdgcn_mfma_f32_16x16x32_f16(kf0, qf[qg][0], z, 0, 0, 0);
        s[sub][qg] = __builtin_amdgcn_mfma_f32_16x16x32_f16(kf1, qf[qg][1], z, 0, 0, 0);
      }
    }
    __builtin_amdgcn_s_setprio(0);

    // P^T = exp2(S^T) packed to f16x4 B-fragments (pure registers, no LDS)
    f16x4 pb[4][2];
#pragma unroll
    for (int sub = 0; sub < 4; ++sub)
#pragma unroll
      for (int qg = 0; qg < 2; ++qg) {
        float e0 = __builtin_amdgcn_exp2f(s[sub][qg][0]);
        float e1 = __builtin_amdgcn_exp2f(s[sub][qg][1]);
        float e2 = __builtin_amdgcn_exp2f(s[sub][qg][2]);
        float e3 = __builtin_amdgcn_exp2f(s[sub][qg][3]);
        psum[qg] += (e0 + e1) + (e2 + e3);
        pb[sub][qg] = pk4(e0, e1, e2, e3);
      }

    // O^T += V^T P^T  (A = V^T[16d][16kv] sub-tiles via b64 reads, B = pb)
    __builtin_amdgcn_s_setprio(1);
#pragma unroll
    for (int dt = 0; dt < 4; ++dt) {
      int dr = dt * 16 + q;           // d row; dr&7 == q&7
#pragma unroll
      for (int ks = 0; ks < 4; ++ks) {
        f16x4 va = *(const f16x4*)(Vc + dr * 128 + (((ks * 2 + (g >> 1)) ^ (q & 7)) << 4) + (g & 1) * 8);
#pragma unroll
        for (int qg = 0; qg < 2; ++qg)
          o[dt][qg] = __builtin_amdgcn_mfma_f32_16x16x16f16(va, pb[ks][qg], o[dt][qg], 0, 0, 0);
      }
    }
    __builtin_amdgcn_s_setprio(0);
    __builtin_amdgcn_s_barrier();   // all waves done reading buf[cur] before restage
  }

  // epilogue: psum reduce (lanes q,q+16,q+32,q+48), per-lane normalize (col=q),
  // LDS transpose (reuse Ks: [64 q][64 d] f16, chunk XOR by qrow&7), coalesced store.
#pragma unroll
  for (int qg = 0; qg < 2; ++qg) {
    psum[qg] += __shfl_xor(psum[qg], 16, 64);
    psum[qg] += __shfl_xor(psum[qg], 32, 64);
  }
  float inv[2] = {1.f / psum[0], 1.f / psum[1]};
  char* TsB = (char*)Ks;
#pragma unroll
  for (int dt = 0; dt < 4; ++dt)
#pragma unroll
    for (int qg = 0; qg < 2; ++qg) {
      f16x4 pv = pk4(o[dt][qg][0] * inv[qg], o[dt][qg][1] * inv[qg],
                     o[dt][qg][2] * inv[qg], o[dt][qg][3] * inv[qg]);
      int qrow = wid * 32 + qg * 16 + q;          // 0..63
      int c = dt * 2 + (g >> 1);
      char* p = TsB + qrow * 128 + ((c ^ (qrow & 7)) << 4) + (g & 1) * 8;
      *(unsigned long long*)p = __builtin_bit_cast(unsigned long long, pv);
    }
  __syncthreads();
  {
    int qrow = threadIdx.x >> 1, half = threadIdx.x & 1;   // 64 rows x 2 halves = 128 threads
    f16* gdst = attout + ((size_t)(b * Tn) + blockIdx.x * 64 + qrow) * Dn + h * 64 + half * 32;
#pragma unroll
    for (int j = 0; j < 4; ++j) {
      int hc = half * 4 + j;
      f16x8 vv = *(const f16x8*)(TsB + qrow * 128 + ((hc ^ (qrow & 7)) << 4));
      *(f16x8*)(gdst + j * 8) = vv;
    }
  }
}

// ---------------- out-proj GEMM: 64x128 tile (2 blocks/CU for occupancy) ----------------
__global__ __launch_bounds__(256) void k_gemm_o(const f16* __restrict__ A, const f16* __restrict__ Bt,
                                                float* __restrict__ C, int N, int K) {
  __shared__ __align__(16) f16 As[64 * 64];
  __shared__ __align__(16) f16 Bs[128 * 64];
  const int lane = threadIdx.x & 63, wid = threadIdx.x >> 6;
  const int m0 = blockIdx.y * 64, n0 = blockIdx.x * 128;
  const int wr = (wid >> 1) * 32, wc = (wid & 1) * 64;
  f32x4 acc[2][4];
#pragma unroll
  for (int i = 0; i < 2; ++i)
#pragma unroll
    for (int j = 0; j < 4; ++j) acc[i][j] = (f32x4){0.f, 0.f, 0.f, 0.f};

  char* AsB = (char*)As; char* BsB = (char*)Bs;
  for (int k0 = 0; k0 < K; k0 += 64) {
    __syncthreads();
#pragma unroll
    for (int it = 0; it < 2; ++it) {
      int flat = ((wid * 2 + it) * 64 + lane) * 16;
      int row = flat >> 7, g = (flat >> 4) & 7;
      int sw = (g ^ (row & 7)) << 4;
      gld16((const char*)A + ((size_t)(m0 + row) * K + k0) * 2 + sw, AsB + (wid * 2 + it) * 1024);
    }
#pragma unroll
    for (int it = 0; it < 4; ++it) {
      int flat = ((wid * 4 + it) * 64 + lane) * 16;
      int row = flat >> 7, g = (flat >> 4) & 7;
      int sw = (g ^ (row & 7)) << 4;
      gld16((const char*)Bt + ((size_t)(n0 + row) * K + k0) * 2 + sw, BsB + (wid * 4 + it) * 1024);
    }
    __syncthreads();
#pragma unroll
    for (int kk = 0; kk < 2; ++kk) {
      f16x8 af[2], bf[4];
#pragma unroll
      for (int ms = 0; ms < 2; ++ms) {
        int r = wr + ms * 16 + (lane & 15);
        af[ms] = *(const f16x8*)(AsB + r * 128 + (((kk * 4 + (lane >> 4)) ^ (r & 7)) << 4));
      }
#pragma unroll
      for (int ns = 0; ns < 4; ++ns) {
        int r = wc + ns * 16 + (lane & 15);
        bf[ns] = *(const f16x8*)(BsB + r * 128 + (((kk * 4 + (lane >> 4)) ^ (r & 7)) << 4));
      }
#pragma unroll
      for (int ms = 0; ms < 2; ++ms)
#pragma unroll
        for (int ns = 0; ns < 4; ++ns)
          acc[ms][ns] = __builtin_amdgcn_mfma_f32_16x16x32_f16(af[ms], bf[ns], acc[ms][ns], 0, 0, 0);
    }
  }
  const int rq = lane >> 4, cq = lane & 15;
#pragma unroll
  for (int ms = 0; ms < 2; ++ms)
#pragma unroll
    for (int ns = 0; ns < 4; ++ns)
#pragma unroll
      for (int r = 0; r < 4; ++r)
        C[(size_t)(m0 + wr + ms * 16 + rq * 4 + r) * N + n0 + wc + ns * 16 + cq] = acc[ms][ns][r];
}

// ---------------- host launch ----------------
extern "C" void kernel_launch(void* const* d_in, const int* in_sizes, int n_in,
                              void* d_out, int out_size, void* d_ws, size_t ws_size,
                              hipStream_t stream) {
  const float* x  = (const float*)d_in[0];
  const float* wq = (const float*)d_in[1];
  const float* wk = (const float*)d_in[2];
  const float* wv = (const float*)d_in[3];
  const float* wo = (const float*)d_in[4];
  const float* qw = (const float*)d_in[5];
  const float* kw = (const float*)d_in[6];

  char* ws = (char*)d_ws;
  const size_t MB = 1 << 20;
  f16* xb     = (f16*)(ws + 0 * MB);    // 8 MB
  f16* wcat   = (f16*)(ws + 8 * MB);    // 6 MB  [3072][1024] head-contiguous rows
  f16* wot    = (f16*)(ws + 14 * MB);   // 2 MB  [1024][1024] = Wo^T
  f16* qatt   = (f16*)(ws + 16 * MB);   // 8 MB  [32][2048][64]
  f16* katt   = (f16*)(ws + 24 * MB);   // 8 MB
  f16* vatt   = (f16*)(ws + 32 * MB);   // 8 MB
  f16* vtb    = (f16*)(ws + 40 * MB);   // 8 MB  [32][64][2048]
  f16* attout = (f16*)(ws + 48 * MB);   // 8 MB  [4096][1024]

  k_prep<<<dim3(5120), 256, 0, stream>>>(x, wq, wk, wv, wo, xb, wcat, wot);
  k_gemm_qkv<<<dim3(NQKV / 128, Mn / 128), 256, 0, stream>>>(xb, wcat, qw, kw, qatt, katt, vatt);
  k_vtrans<<<dim3(Tn / 64, 32), 256, 0, stream>>>(vatt, vtb);
  k_attn<<<dim3(Tn / 64, 32), 128, 0, stream>>>(qatt, katt, vtb, attout);
  k_gemm_o<<<dim3(Dn / 128, Mn / 64), 256, 0, stream>>>(attout, wot, (float*)d_out, Dn, Dn);
}